// Round 14
// baseline (234.624 us; speedup 1.0000x reference)
//
#include <hip/hip_runtime.h>
#include <hip/hip_bf16.h>
#include <stdint.h>

// B=2, S=2048, E=1024, H=16, D=64.
// d_out (fp32): out [2,2048,1024] then probs [2,16,2048,2048].
// d_ws (shorts): Xb | Wt(q,k,v,o transposed) | Q | K | V | ctx  (each 4,194,304).
// R14: attn rebuilt as 8-wave/512-thread blocks, wave-level q-tile split:
// loop A = one K-traversal for all 128 rows' sums; loop B = one traversal for
// probs+PV. 2 traversals (vs 3), 64 sync events (vs 96), 16 waves/CU (vs 8),
// per-thread regs ~R10-light. Ps is half-K; PV in 2 halves w/ wave-private refill.

typedef __attribute__((ext_vector_type(8))) short bf16x8;
typedef __attribute__((ext_vector_type(4))) short bf16x4v;
typedef __attribute__((ext_vector_type(4))) float f32x4;

#define DEV static __device__ __forceinline__

DEV short f2bs(float f) {
  union { __hip_bfloat16 b; short s; } u;
  u.b = __float2bfloat16(f);
  return u.s;
}
DEV f32x4 mfma16(bf16x8 a, bf16x8 b, f32x4 c) {
  return __builtin_amdgcn_mfma_f32_16x16x32_bf16(a, b, c, 0, 0, 0);
}
DEV float fexp2(float x) { return __builtin_amdgcn_exp2f(x); }
typedef const __attribute__((address_space(1))) void* gas1_t;
typedef __attribute__((address_space(3))) void* las3_t;
DEV void gload_lds16(const void* g, void* l) {
  // LDS dest is wave-uniform base + lane*16; global src is per-lane.
  __builtin_amdgcn_global_load_lds((gas1_t)(uintptr_t)g, (las3_t)(uint32_t)(uintptr_t)l,
                                   16, 0, 0);
}
#define WAIT_VMCNT(N) asm volatile("s_waitcnt vmcnt(" #N ")" ::: "memory")
#define WAIT_LGKM0() asm volatile("s_waitcnt lgkmcnt(0)" ::: "memory")
#define BARRIER() do { __builtin_amdgcn_s_barrier(); __builtin_amdgcn_sched_barrier(0); } while (0)

// ---------- fused converts: X fp32->bf16, W [k][n] fp32 -> Wt [mat][n][k] bf16 ----------
__global__ void cvt_all_kernel(const float* __restrict__ X,
                               const float* __restrict__ Wq, const float* __restrict__ Wk,
                               const float* __restrict__ Wv, const float* __restrict__ Wo,
                               short* __restrict__ Xb, short* __restrict__ Wt) {
  __shared__ short tile[64][68];
  int bx = blockIdx.x, t = threadIdx.x;
  if (bx < 2048) {
    size_t i = (size_t)bx * 256 + t;
    const float4* X4 = (const float4*)X;
    float4 a = X4[2 * i], c = X4[2 * i + 1];
    bf16x8 o;
    o[0] = f2bs(a.x); o[1] = f2bs(a.y); o[2] = f2bs(a.z); o[3] = f2bs(a.w);
    o[4] = f2bs(c.x); o[5] = f2bs(c.y); o[6] = f2bs(c.z); o[7] = f2bs(c.w);
    *(bf16x8*)(Xb + i * 8) = o;
    return;
  }
  int wb = bx - 2048;
  int mat = wb >> 8, rem = wb & 255;
  const float* W = mat == 0 ? Wq : mat == 1 ? Wk : mat == 2 ? Wv : Wo;
  int kb = (rem >> 4) * 64, nb = (rem & 15) * 64;
#pragma unroll
  for (int it = 0; it < 4; ++it) {
    int idx = it * 256 + t;
    int row = idx >> 4, c4 = (idx & 15) * 4;
    float4 v = *(const float4*)(W + (size_t)(kb + row) * 1024 + nb + c4);
    tile[row][c4 + 0] = f2bs(v.x); tile[row][c4 + 1] = f2bs(v.y);
    tile[row][c4 + 2] = f2bs(v.z); tile[row][c4 + 3] = f2bs(v.w);
  }
  __syncthreads();
#pragma unroll
  for (int it = 0; it < 4; ++it) {
    int idx = it * 256 + t;
    int rn = idx >> 4, c4 = (idx & 15) * 4;
    bf16x4v o;
    o[0] = tile[c4 + 0][rn]; o[1] = tile[c4 + 1][rn];
    o[2] = tile[c4 + 2][rn]; o[3] = tile[c4 + 3][rn];
    *(bf16x4v*)(Wt + (((size_t)mat) << 20) + (size_t)(nb + rn) * 1024 + kb + c4) = o;
  }
}

// ---------- GEMM: A[M][1024] bf16 @ Bt[N][1024] bf16, BK=64, XOR-swizzled LDS ----------
// MODE 0: 128x128 tile (QKV proj). MODE 1: 128x64 tile (out proj, 2-3 blocks/CU).
template <int MODE, int GBX>
__global__ __launch_bounds__(256, MODE == 0 ? 2 : 3)
void gemm_bt_kernel(const short* __restrict__ A, const short* __restrict__ Bt,
                    const float* __restrict__ bias0, const float* __restrict__ bias1,
                    const float* __restrict__ bias2,
                    short* __restrict__ o0, short* __restrict__ o1, short* __restrict__ o2,
                    float* __restrict__ fout) {
  constexpr int BN = (MODE == 0) ? 128 : 64;
  constexpr int NBLINES = BN / 32;
  __shared__ short As[2][128 * 64];
  __shared__ short Bs[2][BN * 64];
  const int nwg = GBX * gridDim.y;
  const int cpx = nwg >> 3;  // nwg % 8 == 0 for our grids
  const int bid0 = blockIdx.y * GBX + blockIdx.x;
  const int bid = (bid0 % 8) * cpx + bid0 / 8;  // bijective XCD swizzle
  const int m0 = (bid % GBX) * 128, n0 = (bid / GBX) * BN;
  const int t = threadIdx.x, w = t >> 6, l = t & 63, g = l >> 4, r = l & 15;
  const int lr = l >> 3, lc = l & 7;
  const int swz = lc ^ lr;  // source col-unit XOR (row&7 == lr at our staging bases)
  const int wr = (w >> 1) * 64, wc = (w & 1) * (BN / 2);
  f32x4 acc[4][BN / 32] = {};

#define STAGE_G(k0_, b_)                                                                \
  do {                                                                                  \
    _Pragma("unroll") for (int it_ = 0; it_ < 4; ++it_)                                 \
        gload_lds16(A + (size_t)(m0 + it_ * 32 + w * 8 + lr) * 1024 + (k0_) + swz * 8,  \
                    As[b_] + (it_ * 32 + w * 8) * 64);                                  \
    _Pragma("unroll") for (int it_ = 0; it_ < NBLINES; ++it_)                           \
        gload_lds16(Bt + (size_t)(n0 + it_ * 32 + w * 8 + lr) * 1024 + (k0_) + swz * 8, \
                    Bs[b_] + (it_ * 32 + w * 8) * 64);                                  \
  } while (0)

  STAGE_G(0, 0);
  for (int it = 0; it < 16; ++it) {
    const int cur = it & 1;
    if (it < 15) {
      STAGE_G((it + 1) * 64, cur ^ 1);
      if constexpr (MODE == 0) { WAIT_VMCNT(8); } else { WAIT_VMCNT(6); }
    } else {
      WAIT_VMCNT(0);
    }
    BARRIER();
    bf16x8 af[2][4], bfv[2][BN / 32];
#pragma unroll
    for (int df = 0; df < 2; df++) {
#pragma unroll
      for (int i = 0; i < 4; i++)
        af[df][i] = *(const bf16x8*)(As[cur] + (wr + i * 16 + r) * 64 +
                                     ((df * 4 + g) ^ (r & 7)) * 8);
#pragma unroll
      for (int j = 0; j < BN / 32; j++)
        bfv[df][j] = *(const bf16x8*)(Bs[cur] + (wc + j * 16 + r) * 64 +
                                      ((df * 4 + g) ^ (r & 7)) * 8);
    }
    __builtin_amdgcn_s_setprio(1);
#pragma unroll
    for (int df = 0; df < 2; df++)
#pragma unroll
      for (int i = 0; i < 4; i++)
#pragma unroll
        for (int j = 0; j < BN / 32; j++)
          acc[i][j] = mfma16(af[df][i], bfv[df][j], acc[i][j]);
    __builtin_amdgcn_s_setprio(0);
    BARRIER();
  }
#undef STAGE_G
  if constexpr (MODE == 0) {
#pragma unroll
    for (int j = 0; j < 4; j++) {
      int ng = n0 + wc + j * 16 + r;
      int mat = ng >> 10, nn = ng & 1023, hh = nn >> 6, dd = nn & 63;
      const float* bp = mat == 0 ? bias0 : (mat == 1 ? bias1 : bias2);
      short* dst = mat == 0 ? o0 : (mat == 1 ? o1 : o2);
      float bv = bp[nn];
      float sc = (mat == 0) ? 0.18033688f : 1.0f;  // 1/sqrt(D) * log2(e) folded into Q
#pragma unroll
      for (int i = 0; i < 4; i++) {
#pragma unroll
        for (int q = 0; q < 4; q++) {
          int m = m0 + wr + i * 16 + g * 4 + q;
          int bb = m >> 11, ss = m & 2047;
          dst[((size_t)(bb * 16 + hh) * 2048 + ss) * 64 + dd] = f2bs((acc[i][j][q] + bv) * sc);
        }
      }
    }
  } else {
#pragma unroll
    for (int i = 0; i < 4; i++)
#pragma unroll
      for (int q = 0; q < 4; q++) {
        int m = m0 + wr + i * 16 + g * 4 + q;
#pragma unroll
        for (int j = 0; j < 2; j++) {
          int ng = n0 + wc + j * 16 + r;
          fout[(size_t)m * 1024 + ng] = acc[i][j][q] + bias0[ng];
        }
      }
  }
}

// ---------- fused attention: 8 waves x 16 q-rows, 2 K-traversals ----------
// Block = (b,h) x 128 q-rows, 512 threads. Wave w owns rows [w*16, w*16+16).
// Loop A: one traversal, all sums (rinv kept in-register per wave).
// Loop B: one traversal, probs + PV for all rows; Ps half-K [16][72] with
// wave-private refill between PV halves (same-wave DS FIFO orders WAR/RAW).
// vmcnt ledgers: A steady=2, last=0. B: kt0=4 (V2+S2), steady=12 (st8+V2+S2),
// last=10 (st8+V2).
__global__ __launch_bounds__(512, 4)
void attn_kernel(const short* __restrict__ Qm, const short* __restrict__ Km,
                 const short* __restrict__ Vm, float* __restrict__ probs,
                 short* __restrict__ ctx) {
  __shared__ short Ks[2][128 * 64];  // K tiles (32 KB); Q slab staged in Ks[0] first
  __shared__ short Vt[64 * 136];     // V^T [64 d][128 k + pad], 8-short-unit XOR swizzle
  __shared__ short Ps[8][16 * 72];   // per-wave P bf16 [16 q][64 k] (half-K)
  __shared__ float rls[128];         // 1/l per slab row (ctx epilogue only)
  const int f = blockIdx.x;
  const int wgid = (f & 7) * 64 + (f >> 3);      // bijective XCD swizzle (nwg=512)
  const int bh = wgid >> 4, q0 = (wgid & 15) * 128;
  const int bb = bh >> 4, hh = bh & 15;
  const short* Qp = Qm + (size_t)bh * 2048 * 64;
  const short* Kp = Km + (size_t)bh * 2048 * 64;
  const short* Vp = Vm + (size_t)bh * 2048 * 64;
  float* Pp = probs + (size_t)bh * 2048 * 2048;
  const int t = threadIdx.x, w = t >> 6, l = t & 63, g = l >> 4, r = l & 15;
  const int lr = l >> 3, lc = l & 7;
  const int swz = lc ^ lr;  // 16B-unit source swizzle for K/Q staging

  // 512 threads: one STAGE covers 64 rows -> 2 issues per 128-row tile.
#define STAGE_K(kt_, buf_)                                                            \
  do {                                                                                \
    const short* src_ = Kp + (size_t)((kt_) * 128) * 64;                              \
    _Pragma("unroll") for (int it_ = 0; it_ < 2; ++it_)                               \
        gload_lds16(src_ + (size_t)(it_ * 64 + w * 8 + lr) * 64 + swz * 8,            \
                    Ks[buf_] + (it_ * 64 + w * 8) * 64);                              \
  } while (0)

  // ---- prologue: stage Q slab (128 rows) into Ks[0]; hoist wave's fragments ----
#pragma unroll
  for (int it = 0; it < 2; ++it)
    gload_lds16(Qp + (size_t)(q0 + it * 64 + w * 8 + lr) * 64 + swz * 8,
                Ks[0] + (it * 64 + w * 8) * 64);
  __syncthreads();
  bf16x8 qf[2];
#pragma unroll
  for (int df = 0; df < 2; df++)
    qf[df] = *(const bf16x8*)(Ks[0] + (w * 16 + r) * 64 + ((df * 4 + g) ^ (r & 7)) * 8);
  WAIT_LGKM0();
  BARRIER();  // fragments in regs; Ks buffers free

  // -------- loop A: one traversal, all 128 rows' sums --------
  float lrow = 0.f;
  STAGE_K(0, 0);
  for (int kt = 0; kt < 16; ++kt) {
    const int cur = kt & 1;
    if (kt < 15) {
      STAGE_K(kt + 1, cur ^ 1);
      WAIT_VMCNT(2);
    } else {
      WAIT_VMCNT(0);
    }
    BARRIER();
    f32x4 st[8] = {};
    __builtin_amdgcn_s_setprio(1);
#pragma unroll
    for (int df = 0; df < 2; ++df) {
      bf16x8 kf[8];
#pragma unroll
      for (int ni = 0; ni < 8; ni++)
        kf[ni] = *(const bf16x8*)(Ks[cur] + (ni * 16 + r) * 64 + ((df * 4 + g) ^ (r & 7)) * 8);
#pragma unroll
      for (int ni = 0; ni < 8; ni++) st[ni] = mfma16(kf[ni], qf[df], st[ni]);
    }
    __builtin_amdgcn_s_setprio(0);
    float ssum = 0.f;
#pragma unroll
    for (int ni = 0; ni < 8; ni++)
#pragma unroll
      for (int q4 = 0; q4 < 4; q4++) ssum += fexp2(st[ni][q4]);
    ssum += __shfl_xor(ssum, 16);
    ssum += __shfl_xor(ssum, 32);
    lrow += ssum;
    BARRIER();  // all waves done reading Ks[cur] before next STAGE overwrites
  }
  const float rinv = 1.0f / lrow;  // lane (g,r): 1/l of slab row w*16+r
  if (g == 0) rls[w * 16 + r] = rinv;

  // V helper indices (512 threads: each thread loads 2 V rows: kp, kp+1)
  const int kp = (t >> 3) * 2;        // 0..126 even, covers all 128 rows
  const int d0v = (t & 7) * 8;        // d-chunk
  const int lcv = t & 7, kunit = t >> 5;  // kunit = kp>>3 in [0,16)

  // -------- loop B: one traversal, probs + PV for all rows --------
  f32x4 cacc[4] = {};
  STAGE_K(0, 0);
  for (int kt = 0; kt < 16; ++kt) {
    const int cur = kt & 1;
    bf16x8 v0 = *(const bf16x8*)(Vp + (size_t)(kt * 128 + kp) * 64 + d0v);
    bf16x8 v1 = *(const bf16x8*)(Vp + (size_t)(kt * 128 + kp + 1) * 64 + d0v);
    if (kt < 15) STAGE_K(kt + 1, cur ^ 1);
    if (kt == 0) { WAIT_VMCNT(4); }
    else if (kt < 15) { WAIT_VMCNT(12); }
    else { WAIT_VMCNT(10); }
    BARRIER();
    // QK^T: 16 MFMA, wave's own 16 q-rows vs full 128-k tile
    f32x4 st[8] = {};
    __builtin_amdgcn_s_setprio(1);
#pragma unroll
    for (int df = 0; df < 2; ++df) {
      bf16x8 kf[8];
#pragma unroll
      for (int ni = 0; ni < 8; ni++)
        kf[ni] = *(const bf16x8*)(Ks[cur] + (ni * 16 + r) * 64 + ((df * 4 + g) ^ (r & 7)) * 8);
#pragma unroll
      for (int ni = 0; ni < 8; ni++) st[ni] = mfma16(kf[ni], qf[df], st[ni]);
    }
    __builtin_amdgcn_s_setprio(0);
    // P = exp2(s): fp32 kept for probs; bf16 packs in regs
    bf16x4v pk[8];
#pragma unroll
    for (int ni = 0; ni < 8; ni++) {
#pragma unroll
      for (int q4 = 0; q4 < 4; q4++) {
        float pe = fexp2(st[ni][q4]);
        st[ni][q4] = pe;
        pk[ni][q4] = f2bs(pe);
      }
    }
    // Ps <- half0 (k 0..63); V^T full tile (each thread 8 u32)
#pragma unroll
    for (int ni = 0; ni < 4; ni++)
      *(bf16x4v*)(&Ps[w][r * 72 + ni * 16 + g * 4]) = pk[ni];
#pragma unroll
    for (int e = 0; e < 8; e++) {
      unsigned int pv_ = (unsigned int)(unsigned short)v0[e] |
                         ((unsigned int)(unsigned short)v1[e] << 16);
      int su_ = (kunit & 8) | ((kunit & 7) ^ lcv);
      *(unsigned int*)(Vt + (d0v + e) * 136 + (su_ << 3) + (kp & 7)) = pv_;
    }
    WAIT_LGKM0();
    BARRIER();
    // probs stores: 8 f32x4/lane (rows = wave's own; full-line coalesced)
#pragma unroll
    for (int ni = 0; ni < 8; ni++) {
      f32x4 pr;
#pragma unroll
      for (int q4 = 0; q4 < 4; q4++) pr[q4] = st[ni][q4] * rinv;
      *(f32x4*)(Pp + (size_t)(q0 + w * 16 + r) * 2048 + kt * 128 + ni * 16 + g * 4) = pr;
    }
    // PV half0: k 0..63 (Vt units 0..7)
    __builtin_amdgcn_s_setprio(1);
#pragma unroll
    for (int kf4 = 0; kf4 < 2; ++kf4) {
      bf16x8 pa, vb[4];
      pa = *(const bf16x8*)(&Ps[w][r * 72 + kf4 * 32 + g * 8]);
#pragma unroll
      for (int nj = 0; nj < 4; nj++) {
        int u_ = kf4 * 4 + g, x_ = nj * 2 + (r >> 3);
        vb[nj] = *(const bf16x8*)(Vt + (nj * 16 + r) * 136 + ((u_ ^ x_) << 3));
      }
#pragma unroll
      for (int nj = 0; nj < 4; nj++) cacc[nj] = mfma16(pa, vb[nj], cacc[nj]);
    }
    __builtin_amdgcn_s_setprio(0);
    // Ps <- half1 (k 64..127) — wave-private; same-wave DS FIFO orders vs PV0 reads
#pragma unroll
    for (int ni = 4; ni < 8; ni++)
      *(bf16x4v*)(&Ps[w][r * 72 + (ni - 4) * 16 + g * 4]) = pk[ni];
    // PV half1: k 64..127 (Vt units 8..15)
    __builtin_amdgcn_s_setprio(1);
#pragma unroll
    for (int kf4 = 2; kf4 < 4; ++kf4) {
      bf16x8 pa, vb[4];
      pa = *(const bf16x8*)(&Ps[w][r * 72 + (kf4 - 2) * 32 + g * 8]);
#pragma unroll
      for (int nj = 0; nj < 4; nj++) {
        int u_ = kf4 * 4 + g, x_ = nj * 2 + (r >> 3);
        int su_ = (u_ & 8) | ((u_ & 7) ^ x_);
        vb[nj] = *(const bf16x8*)(Vt + (nj * 16 + r) * 136 + (su_ << 3));
      }
#pragma unroll
      for (int nj = 0; nj < 4; nj++) cacc[nj] = mfma16(pa, vb[nj], cacc[nj]);
    }
    __builtin_amdgcn_s_setprio(0);
  }
  // ctx epilogue: wave's own 16 rows
#pragma unroll
  for (int nj = 0; nj < 4; nj++)
#pragma unroll
    for (int q4 = 0; q4 < 4; q4++) {
      int qt = w * 16 + g * 4 + q4;
      float val = cacc[nj][q4] * rls[qt];
      ctx[((size_t)(bb * 2048 + q0 + qt)) * 1024 + hh * 64 + nj * 16 + r] = f2bs(val);
    }
#undef STAGE_K
}

extern "C" void kernel_launch(void* const* d_in, const int* in_sizes, int n_in,
                              void* d_out, int out_size, void* d_ws, size_t ws_size,
                              hipStream_t stream) {
  (void)in_sizes; (void)n_in; (void)out_size; (void)ws_size;
  const float* X  = (const float*)d_in[0];
  const float* Wq = (const float*)d_in[1];
  const float* bq = (const float*)d_in[2];
  const float* Wk = (const float*)d_in[3];
  const float* bk = (const float*)d_in[4];
  const float* Wv = (const float*)d_in[5];
  const float* bv = (const float*)d_in[6];
  const float* Wo = (const float*)d_in[7];
  const float* bo = (const float*)d_in[8];
  float* out = (float*)d_out;
  float* probs = out + (size_t)2 * 2048 * 1024;

  short* Xb = (short*)d_ws;                 // 4096x1024
  short* Wt = Xb + (size_t)4194304;         // 4x1024x1024 (q,k,v,o transposed)
  short* Qb = Wt + (size_t)4194304;         // [B,H,S,D]
  short* Kb = Qb + (size_t)4194304;
  short* Vb = Kb + (size_t)4194304;
  short* Cx = Vb + (size_t)4194304;         // ctx [B,S,E]

  cvt_all_kernel<<<3072, 256, 0, stream>>>(X, Wq, Wk, Wv, Wo, Xb, Wt);
  gemm_bt_kernel<0, 32><<<dim3(32, 24), 256, 0, stream>>>(Xb, Wt, bq, bk, bv,
                                                          Qb, Kb, Vb, nullptr);
  attn_kernel<<<512, 512, 0, stream>>>(Qb, Kb, Vb, probs, Cx);
  gemm_bt_kernel<1, 32><<<dim3(32, 16), 256, 0, stream>>>(Cx, Wt + (size_t)3 * 1048576, bo,
                                                          nullptr, nullptr, nullptr, nullptr,
                                                          nullptr, out);
}

// Round 15
// 212.695 us; speedup vs baseline: 1.1031x; 1.1031x over previous
//
#include <hip/hip_runtime.h>
#include <hip/hip_bf16.h>
#include <stdint.h>

// B=2, S=2048, E=1024, H=16, D=64.
// d_out (fp32): out [2,2048,1024] then probs [2,16,2048,2048].
// d_ws (shorts): Xb | Wt(q,k,v,o transposed) | Q | K | V | ctx  (each 4,194,304).
// R15 = exact revert to R12/R10 (known-best 212.5-212.8 µs): 3-loop attn schedule
// (A(t0); B(t0)||A(t1); B(t1)), KVBLK=128, BK=64 XOR-swizzled GEMMs.

typedef __attribute__((ext_vector_type(8))) short bf16x8;
typedef __attribute__((ext_vector_type(4))) short bf16x4v;
typedef __attribute__((ext_vector_type(4))) float f32x4;

#define DEV static __device__ __forceinline__

DEV short f2bs(float f) {
  union { __hip_bfloat16 b; short s; } u;
  u.b = __float2bfloat16(f);
  return u.s;
}
DEV f32x4 mfma16(bf16x8 a, bf16x8 b, f32x4 c) {
  return __builtin_amdgcn_mfma_f32_16x16x32_bf16(a, b, c, 0, 0, 0);
}
DEV float fexp2(float x) { return __builtin_amdgcn_exp2f(x); }
typedef const __attribute__((address_space(1))) void* gas1_t;
typedef __attribute__((address_space(3))) void* las3_t;
DEV void gload_lds16(const void* g, void* l) {
  // LDS dest is wave-uniform base + lane*16; global src is per-lane.
  __builtin_amdgcn_global_load_lds((gas1_t)(uintptr_t)g, (las3_t)(uint32_t)(uintptr_t)l,
                                   16, 0, 0);
}
#define WAIT_VMCNT(N) asm volatile("s_waitcnt vmcnt(" #N ")" ::: "memory")
#define WAIT_LGKM0() asm volatile("s_waitcnt lgkmcnt(0)" ::: "memory")
#define BARRIER() do { __builtin_amdgcn_s_barrier(); __builtin_amdgcn_sched_barrier(0); } while (0)

// ---------- fused converts: X fp32->bf16, W [k][n] fp32 -> Wt [mat][n][k] bf16 ----------
__global__ void cvt_all_kernel(const float* __restrict__ X,
                               const float* __restrict__ Wq, const float* __restrict__ Wk,
                               const float* __restrict__ Wv, const float* __restrict__ Wo,
                               short* __restrict__ Xb, short* __restrict__ Wt) {
  __shared__ short tile[64][68];
  int bx = blockIdx.x, t = threadIdx.x;
  if (bx < 2048) {
    size_t i = (size_t)bx * 256 + t;
    const float4* X4 = (const float4*)X;
    float4 a = X4[2 * i], c = X4[2 * i + 1];
    bf16x8 o;
    o[0] = f2bs(a.x); o[1] = f2bs(a.y); o[2] = f2bs(a.z); o[3] = f2bs(a.w);
    o[4] = f2bs(c.x); o[5] = f2bs(c.y); o[6] = f2bs(c.z); o[7] = f2bs(c.w);
    *(bf16x8*)(Xb + i * 8) = o;
    return;
  }
  int wb = bx - 2048;
  int mat = wb >> 8, rem = wb & 255;
  const float* W = mat == 0 ? Wq : mat == 1 ? Wk : mat == 2 ? Wv : Wo;
  int kb = (rem >> 4) * 64, nb = (rem & 15) * 64;
#pragma unroll
  for (int it = 0; it < 4; ++it) {
    int idx = it * 256 + t;
    int row = idx >> 4, c4 = (idx & 15) * 4;
    float4 v = *(const float4*)(W + (size_t)(kb + row) * 1024 + nb + c4);
    tile[row][c4 + 0] = f2bs(v.x); tile[row][c4 + 1] = f2bs(v.y);
    tile[row][c4 + 2] = f2bs(v.z); tile[row][c4 + 3] = f2bs(v.w);
  }
  __syncthreads();
#pragma unroll
  for (int it = 0; it < 4; ++it) {
    int idx = it * 256 + t;
    int rn = idx >> 4, c4 = (idx & 15) * 4;
    bf16x4v o;
    o[0] = tile[c4 + 0][rn]; o[1] = tile[c4 + 1][rn];
    o[2] = tile[c4 + 2][rn]; o[3] = tile[c4 + 3][rn];
    *(bf16x4v*)(Wt + (((size_t)mat) << 20) + (size_t)(nb + rn) * 1024 + kb + c4) = o;
  }
}

// ---------- GEMM: A[M][1024] bf16 @ Bt[N][1024] bf16, BK=64, XOR-swizzled LDS ----------
// MODE 0: 128x128 tile (QKV proj). MODE 1: 128x64 tile (out proj, 2-3 blocks/CU).
template <int MODE, int GBX>
__global__ __launch_bounds__(256, MODE == 0 ? 2 : 3)
void gemm_bt_kernel(const short* __restrict__ A, const short* __restrict__ Bt,
                    const float* __restrict__ bias0, const float* __restrict__ bias1,
                    const float* __restrict__ bias2,
                    short* __restrict__ o0, short* __restrict__ o1, short* __restrict__ o2,
                    float* __restrict__ fout) {
  constexpr int BN = (MODE == 0) ? 128 : 64;
  constexpr int NBLINES = BN / 32;
  __shared__ short As[2][128 * 64];
  __shared__ short Bs[2][BN * 64];
  const int nwg = GBX * gridDim.y;
  const int cpx = nwg >> 3;  // nwg % 8 == 0 for our grids
  const int bid0 = blockIdx.y * GBX + blockIdx.x;
  const int bid = (bid0 % 8) * cpx + bid0 / 8;  // bijective XCD swizzle
  const int m0 = (bid % GBX) * 128, n0 = (bid / GBX) * BN;
  const int t = threadIdx.x, w = t >> 6, l = t & 63, g = l >> 4, r = l & 15;
  const int lr = l >> 3, lc = l & 7;
  const int swz = lc ^ lr;  // source col-unit XOR (row&7 == lr at our staging bases)
  const int wr = (w >> 1) * 64, wc = (w & 1) * (BN / 2);
  f32x4 acc[4][BN / 32] = {};

#define STAGE_G(k0_, b_)                                                                \
  do {                                                                                  \
    _Pragma("unroll") for (int it_ = 0; it_ < 4; ++it_)                                 \
        gload_lds16(A + (size_t)(m0 + it_ * 32 + w * 8 + lr) * 1024 + (k0_) + swz * 8,  \
                    As[b_] + (it_ * 32 + w * 8) * 64);                                  \
    _Pragma("unroll") for (int it_ = 0; it_ < NBLINES; ++it_)                           \
        gload_lds16(Bt + (size_t)(n0 + it_ * 32 + w * 8 + lr) * 1024 + (k0_) + swz * 8, \
                    Bs[b_] + (it_ * 32 + w * 8) * 64);                                  \
  } while (0)

  STAGE_G(0, 0);
  for (int it = 0; it < 16; ++it) {
    const int cur = it & 1;
    if (it < 15) {
      STAGE_G((it + 1) * 64, cur ^ 1);
      if constexpr (MODE == 0) { WAIT_VMCNT(8); } else { WAIT_VMCNT(6); }
    } else {
      WAIT_VMCNT(0);
    }
    BARRIER();
    bf16x8 af[2][4], bfv[2][BN / 32];
#pragma unroll
    for (int df = 0; df < 2; df++) {
#pragma unroll
      for (int i = 0; i < 4; i++)
        af[df][i] = *(const bf16x8*)(As[cur] + (wr + i * 16 + r) * 64 +
                                     ((df * 4 + g) ^ (r & 7)) * 8);
#pragma unroll
      for (int j = 0; j < BN / 32; j++)
        bfv[df][j] = *(const bf16x8*)(Bs[cur] + (wc + j * 16 + r) * 64 +
                                      ((df * 4 + g) ^ (r & 7)) * 8);
    }
    __builtin_amdgcn_s_setprio(1);
#pragma unroll
    for (int df = 0; df < 2; df++)
#pragma unroll
      for (int i = 0; i < 4; i++)
#pragma unroll
        for (int j = 0; j < BN / 32; j++)
          acc[i][j] = mfma16(af[df][i], bfv[df][j], acc[i][j]);
    __builtin_amdgcn_s_setprio(0);
    BARRIER();
  }
#undef STAGE_G
  if constexpr (MODE == 0) {
#pragma unroll
    for (int j = 0; j < 4; j++) {
      int ng = n0 + wc + j * 16 + r;
      int mat = ng >> 10, nn = ng & 1023, hh = nn >> 6, dd = nn & 63;
      const float* bp = mat == 0 ? bias0 : (mat == 1 ? bias1 : bias2);
      short* dst = mat == 0 ? o0 : (mat == 1 ? o1 : o2);
      float bv = bp[nn];
      float sc = (mat == 0) ? 0.18033688f : 1.0f;  // 1/sqrt(D) * log2(e) folded into Q
#pragma unroll
      for (int i = 0; i < 4; i++) {
#pragma unroll
        for (int q = 0; q < 4; q++) {
          int m = m0 + wr + i * 16 + g * 4 + q;
          int bb = m >> 11, ss = m & 2047;
          dst[((size_t)(bb * 16 + hh) * 2048 + ss) * 64 + dd] = f2bs((acc[i][j][q] + bv) * sc);
        }
      }
    }
  } else {
#pragma unroll
    for (int i = 0; i < 4; i++)
#pragma unroll
      for (int q = 0; q < 4; q++) {
        int m = m0 + wr + i * 16 + g * 4 + q;
#pragma unroll
        for (int j = 0; j < 2; j++) {
          int ng = n0 + wc + j * 16 + r;
          fout[(size_t)m * 1024 + ng] = acc[i][j][q] + bias0[ng];
        }
      }
  }
}

// ---------- fused attention: 2 q-tiles/block, KVBLK=128 (R7/R10 structure) ----------
// Loop1: A(tile0); loop2: B(tile0)+A(tile1) (shared-K QK^T); loop3: B(tile1).
__global__ __launch_bounds__(256, 2)
void attn_kernel(const short* __restrict__ Qm, const short* __restrict__ Km,
                 const short* __restrict__ Vm, float* __restrict__ probs,
                 short* __restrict__ ctx) {
  __shared__ short Ks[2][128 * 64];  // K tiles (32 KB); Q0/Q1 staged here in prologue
  __shared__ short Vt[64 * 136];     // V^T [64 d][128 k + pad], 8-short-unit XOR swizzle
  __shared__ short Ps[4][16 * 136];  // per-wave P bf16 [16 q][128 k] in MFMA-A layout
  __shared__ float rls[128];         // 1/l per q-row (epilogue only; [64..127] = tile1)
  const int f = blockIdx.x;
  const int wgid = (f & 7) * 64 + (f >> 3);      // bijective XCD swizzle (nwg=512)
  const int bh = wgid >> 4, q0 = (wgid & 15) * 128;
  const int bb = bh >> 4, hh = bh & 15;
  const short* Qp = Qm + (size_t)bh * 2048 * 64;
  const short* Kp = Km + (size_t)bh * 2048 * 64;
  const short* Vp = Vm + (size_t)bh * 2048 * 64;
  float* Pp = probs + (size_t)bh * 2048 * 2048;
  const int t = threadIdx.x, w = t >> 6, l = t & 63, g = l >> 4, r = l & 15;
  const int lr = l >> 3, lc = l & 7;
  const int swz = lc ^ lr;  // 16B-unit source swizzle for K/Q staging

#define STAGE_K(kt_, buf_)                                                            \
  do {                                                                                \
    const short* src_ = Kp + (size_t)((kt_) * 128) * 64;                              \
    _Pragma("unroll") for (int it_ = 0; it_ < 4; ++it_)                               \
        gload_lds16(src_ + (size_t)(it_ * 32 + w * 8 + lr) * 64 + swz * 8,            \
                    Ks[buf_] + (it_ * 32 + w * 8) * 64);                              \
  } while (0)

  // ---- prologue: stage Q0 -> Ks[0], Q1 -> Ks[1]; hoist both tiles' fragments ----
#pragma unroll
  for (int it = 0; it < 2; ++it) {
    gload_lds16(Qp + (size_t)(q0 + it * 32 + w * 8 + lr) * 64 + swz * 8,
                Ks[0] + (it * 32 + w * 8) * 64);
    gload_lds16(Qp + (size_t)(q0 + 64 + it * 32 + w * 8 + lr) * 64 + swz * 8,
                Ks[1] + (it * 32 + w * 8) * 64);
  }
  __syncthreads();
  bf16x8 qf0[2], qf1[2];
#pragma unroll
  for (int df = 0; df < 2; df++) {
    qf0[df] = *(const bf16x8*)(Ks[0] + (w * 16 + r) * 64 + ((df * 4 + g) ^ (r & 7)) * 8);
    qf1[df] = *(const bf16x8*)(Ks[1] + (w * 16 + r) * 64 + ((df * 4 + g) ^ (r & 7)) * 8);
  }
  WAIT_LGKM0();
  BARRIER();  // fragments in regs; Ks buffers free

  // -------- loop 1: A(tile0) — row sums of exp2(s), 16 iters --------
  float lrow0 = 0.f;
  STAGE_K(0, 0);
  for (int kt = 0; kt < 16; ++kt) {
    const int cur = kt & 1;
    if (kt < 15) {
      STAGE_K(kt + 1, cur ^ 1);
      WAIT_VMCNT(4);
    } else {
      WAIT_VMCNT(0);
    }
    BARRIER();
    f32x4 st[8] = {};
    __builtin_amdgcn_s_setprio(1);
#pragma unroll
    for (int df = 0; df < 2; ++df) {
      bf16x8 kf[8];
#pragma unroll
      for (int ni = 0; ni < 8; ni++)
        kf[ni] = *(const bf16x8*)(Ks[cur] + (ni * 16 + r) * 64 + ((df * 4 + g) ^ (r & 7)) * 8);
#pragma unroll
      for (int ni = 0; ni < 8; ni++) st[ni] = mfma16(kf[ni], qf0[df], st[ni]);
    }
    __builtin_amdgcn_s_setprio(0);
    float ssum = 0.f;
#pragma unroll
    for (int ni = 0; ni < 8; ni++)
#pragma unroll
      for (int q4 = 0; q4 < 4; q4++) ssum += fexp2(st[ni][q4]);
    ssum += __shfl_xor(ssum, 16);
    ssum += __shfl_xor(ssum, 32);
    lrow0 += ssum;
    BARRIER();  // all waves done reading Ks[cur] before next STAGE overwrites
  }
  const float rinv0 = 1.0f / lrow0;
  if (g == 0) rls[w * 16 + r] = rinv0;

  // V-transpose helper indices: each thread loads 4 V rows (kp,kp+1,kp+64,kp+65)
  const int kp = (t >> 3) * 2, d0v = (t & 7) * 8, lcv = t & 7, kunit = t >> 5;

#define B_TILE_BODY(stv_, qrow_, rinv_)                                                \
  do {                                                                                 \
    /* P = exp2(s): fp32 kept for probs, bf16 copy into Ps */                          \
    _Pragma("unroll") for (int ni = 0; ni < 8; ni++) {                                 \
      bf16x4v pk;                                                                      \
      _Pragma("unroll") for (int q4 = 0; q4 < 4; q4++) {                               \
        float pe = fexp2((stv_)[ni][q4]);                                              \
        (stv_)[ni][q4] = pe;                                                           \
        pk[q4] = f2bs(pe);                                                             \
      }                                                                                \
      *(bf16x4v*)(&Ps[w][r * 136 + ni * 16 + g * 4]) = pk;                             \
    }                                                                                  \
    /* V^T into LDS: unit = (ul&8)|((ul&7)^lcv), ul = k/8 */                           \
    _Pragma("unroll") for (int e = 0; e < 8; e++) {                                    \
      unsigned int p0_ = (unsigned int)(unsigned short)v0[e] |                         \
                         ((unsigned int)(unsigned short)v1[e] << 16);                  \
      unsigned int p1_ = (unsigned int)(unsigned short)v2[e] |                         \
                         ((unsigned int)(unsigned short)v3[e] << 16);                  \
      *(unsigned int*)(Vt + (d0v + e) * 136 + ((kunit ^ lcv) << 3) + (kp & 7)) = p0_;  \
      *(unsigned int*)(Vt + (d0v + e) * 136 + ((8 + (kunit ^ lcv)) << 3) + (kp & 7)) = p1_; \
    }                                                                                  \
    WAIT_LGKM0();                                                                      \
    BARRIER();                                                                         \
    /* probs stores: 8 f32x4/lane, each instr = 16 fully-covered 64B lines */          \
    _Pragma("unroll") for (int ni = 0; ni < 8; ni++) {                                 \
      f32x4 pr;                                                                        \
      _Pragma("unroll") for (int q4 = 0; q4 < 4; q4++) pr[q4] = (stv_)[ni][q4] * (rinv_); \
      *(f32x4*)(Pp + (size_t)((qrow_) + w * 16 + r) * 2048 + kt * 128 + ni * 16 + g * 4) = pr; \
    }                                                                                  \
    /* PV: A = P (own wave rows), B = V^T (cols d), 16 MFMA */                         \
    __builtin_amdgcn_s_setprio(1);                                                     \
    _Pragma("unroll") for (int kf4 = 0; kf4 < 4; ++kf4) {                              \
      bf16x8 pa, vb[4];                                                                \
      pa = *(const bf16x8*)(&Ps[w][r * 136 + kf4 * 32 + g * 8]);                       \
      _Pragma("unroll") for (int nj = 0; nj < 4; nj++) {                               \
        int u_ = kf4 * 4 + g, x_ = nj * 2 + (r >> 3);                                  \
        int su_ = (u_ & 8) | ((u_ & 7) ^ x_);                                          \
        vb[nj] = *(const bf16x8*)(Vt + (nj * 16 + r) * 136 + (su_ << 3));              \
      }                                                                                \
      _Pragma("unroll") for (int nj = 0; nj < 4; nj++)                                 \
          cacc[nj] = mfma16(pa, vb[nj], cacc[nj]);                                     \
    }                                                                                  \
    __builtin_amdgcn_s_setprio(0);                                                     \
  } while (0)

  // -------- loop 2: B(tile0) fused with A(tile1), 16 iters --------
  f32x4 cacc[4] = {};
  float lrow1 = 0.f;
  STAGE_K(0, 0);
  for (int kt = 0; kt < 16; ++kt) {
    const int cur = kt & 1;
    bf16x8 v0 = *(const bf16x8*)(Vp + (size_t)(kt * 128 + kp) * 64 + d0v);
    bf16x8 v1 = *(const bf16x8*)(Vp + (size_t)(kt * 128 + kp + 1) * 64 + d0v);
    bf16x8 v2 = *(const bf16x8*)(Vp + (size_t)(kt * 128 + 64 + kp) * 64 + d0v);
    bf16x8 v3 = *(const bf16x8*)(Vp + (size_t)(kt * 128 + 64 + kp + 1) * 64 + d0v);
    if (kt < 15) STAGE_K(kt + 1, cur ^ 1);
    if (kt == 0) { WAIT_VMCNT(8); }
    else if (kt < 15) { WAIT_VMCNT(16); }
    else { WAIT_VMCNT(12); }
    BARRIER();
    f32x4 st0[8] = {}, st1[8] = {};
    __builtin_amdgcn_s_setprio(1);
#pragma unroll
    for (int df = 0; df < 2; ++df) {
      bf16x8 kf[8];
#pragma unroll
      for (int ni = 0; ni < 8; ni++)
        kf[ni] = *(const bf16x8*)(Ks[cur] + (ni * 16 + r) * 64 + ((df * 4 + g) ^ (r & 7)) * 8);
#pragma unroll
      for (int ni = 0; ni < 8; ni++) {
        st0[ni] = mfma16(kf[ni], qf0[df], st0[ni]);
        st1[ni] = mfma16(kf[ni], qf1[df], st1[ni]);
      }
    }
    __builtin_amdgcn_s_setprio(0);
    {
      float ssum = 0.f;
#pragma unroll
      for (int ni = 0; ni < 8; ni++)
#pragma unroll
        for (int q4 = 0; q4 < 4; q4++) ssum += fexp2(st1[ni][q4]);
      ssum += __shfl_xor(ssum, 16);
      ssum += __shfl_xor(ssum, 32);
      lrow1 += ssum;
    }
    B_TILE_BODY(st0, q0, rinv0);
  }
  // ctx epilogue tile0
#pragma unroll
  for (int nj = 0; nj < 4; nj++)
#pragma unroll
    for (int q4 = 0; q4 < 4; q4++) {
      int qt = w * 16 + g * 4 + q4;
      float val = cacc[nj][q4] * rls[qt];
      ctx[((size_t)(bb * 2048 + q0 + qt)) * 1024 + hh * 64 + nj * 16 + r] = f2bs(val);
    }

  // -------- loop 3: B(tile1), 16 iters --------
  const float rinv1 = 1.0f / lrow1;
  if (g == 0) rls[64 + w * 16 + r] = rinv1;
#pragma unroll
  for (int nj = 0; nj < 4; nj++) cacc[nj] = (f32x4){0.f, 0.f, 0.f, 0.f};
  STAGE_K(0, 0);
  for (int kt = 0; kt < 16; ++kt) {
    const int cur = kt & 1;
    bf16x8 v0 = *(const bf16x8*)(Vp + (size_t)(kt * 128 + kp) * 64 + d0v);
    bf16x8 v1 = *(const bf16x8*)(Vp + (size_t)(kt * 128 + kp + 1) * 64 + d0v);
    bf16x8 v2 = *(const bf16x8*)(Vp + (size_t)(kt * 128 + 64 + kp) * 64 + d0v);
    bf16x8 v3 = *(const bf16x8*)(Vp + (size_t)(kt * 128 + 64 + kp + 1) * 64 + d0v);
    if (kt < 15) STAGE_K(kt + 1, cur ^ 1);
    if (kt == 0) { WAIT_VMCNT(8); }
    else if (kt < 15) { WAIT_VMCNT(16); }
    else { WAIT_VMCNT(12); }
    BARRIER();
    f32x4 st[8] = {};
    __builtin_amdgcn_s_setprio(1);
#pragma unroll
    for (int df = 0; df < 2; ++df) {
      bf16x8 kf[8];
#pragma unroll
      for (int ni = 0; ni < 8; ni++)
        kf[ni] = *(const bf16x8*)(Ks[cur] + (ni * 16 + r) * 64 + ((df * 4 + g) ^ (r & 7)) * 8);
#pragma unroll
      for (int ni = 0; ni < 8; ni++) st[ni] = mfma16(kf[ni], qf1[df], st[ni]);
    }
    __builtin_amdgcn_s_setprio(0);
    B_TILE_BODY(st, q0 + 64, rinv1);
  }
  // ctx epilogue tile1
#pragma unroll
  for (int nj = 0; nj < 4; nj++)
#pragma unroll
    for (int q4 = 0; q4 < 4; q4++) {
      int qt = w * 16 + g * 4 + q4;
      float val = cacc[nj][q4] * rls[64 + qt];
      ctx[((size_t)(bb * 2048 + q0 + 64 + qt)) * 1024 + hh * 64 + nj * 16 + r] = f2bs(val);
    }
#undef B_TILE_BODY
#undef STAGE_K
}

extern "C" void kernel_launch(void* const* d_in, const int* in_sizes, int n_in,
                              void* d_out, int out_size, void* d_ws, size_t ws_size,
                              hipStream_t stream) {
  (void)in_sizes; (void)n_in; (void)out_size; (void)ws_size;
  const float* X  = (const float*)d_in[0];
  const float* Wq = (const float*)d_in[1];
  const float* bq = (const float*)d_in[2];
  const float* Wk = (const float*)d_in[3];
  const float* bk = (const float*)d_in[4];
  const float* Wv = (const float*)d_in[5];
  const float* bv = (const float*)d_in[6];
  const float* Wo = (const float*)d_in[7];
  const float* bo = (const float*)d_in[8];
  float* out = (float*)d_out;
  float* probs = out + (size_t)2 * 2048 * 1024;

  short* Xb = (short*)d_ws;                 // 4096x1024
  short* Wt = Xb + (size_t)4194304;         // 4x1024x1024 (q,k,v,o transposed)
  short* Qb = Wt + (size_t)4194304;         // [B,H,S,D]
  short* Kb = Qb + (size_t)4194304;
  short* Vb = Kb + (size_t)4194304;
  short* Cx = Vb + (size_t)4194304;         // ctx [B,S,E]

  cvt_all_kernel<<<3072, 256, 0, stream>>>(X, Wq, Wk, Wv, Wo, Xb, Wt);
  gemm_bt_kernel<0, 32><<<dim3(32, 24), 256, 0, stream>>>(Xb, Wt, bq, bk, bv,
                                                          Qb, Kb, Vb, nullptr);
  attn_kernel<<<512, 256, 0, stream>>>(Qb, Kb, Vb, probs, Cx);
  gemm_bt_kernel<1, 32><<<dim3(32, 16), 256, 0, stream>>>(Cx, Wt + (size_t)3 * 1048576, bo,
                                                          nullptr, nullptr, nullptr, nullptr,
                                                          nullptr, out);
}